// Round 1
// baseline (419.657 us; speedup 1.0000x reference)
//
#include <hip/hip_runtime.h>
#include <stdint.h>

// Pipeline: (1) normalize keys -> bf16 + invk, (2) bf16-MFMA partitioned
// top-4-per-stream candidate generation (selection is scale-invariant in q),
// (3) exact fp32 refine of top-16 candidates -> top-8, softmax, gather.
// ws layout: [kn_bf16: N*128*2 B][invk: N*4 B][cand: Q*P*64*8 B]

typedef unsigned int u32;
typedef unsigned long long u64;
typedef unsigned short u16;
typedef __attribute__((ext_vector_type(4))) float f32x4;
typedef __attribute__((ext_vector_type(2))) float f32x2;
typedef __attribute__((ext_vector_type(4))) int i32x4;
typedef __attribute__((ext_vector_type(8))) short s16x8;  // 8 bf16 in 4 VGPRs

#define D 128

__device__ __forceinline__ u16 f2bf(float f) {           // RNE float->bf16
    u32 b = __float_as_uint(f);
    b += 0x7FFFu + ((b >> 16) & 1u);
    return (u16)(b >> 16);
}
__device__ __forceinline__ u32 ford(float f) {            // order-preserving f32->u32
    u32 b = __float_as_uint(f);
    return (b & 0x80000000u) ? ~b : (b | 0x80000000u);
}
__device__ __forceinline__ float ford_inv(u32 ob) {
    u32 b = (ob & 0x80000000u) ? (ob ^ 0x80000000u) : ~ob;
    return __uint_as_float(b);
}

// ---------------- kernel 1: normalize keys -> bf16, store 1/max(norm,eps) ---
__global__ __launch_bounds__(256) void k_norm_keys(
        const float* __restrict__ keys, u16* __restrict__ kn,
        float* __restrict__ invk, int N) {
    int row = blockIdx.x * 4 + (threadIdx.x >> 6);
    int lane = threadIdx.x & 63;
    if (row >= N) return;
    const float* kr = keys + (size_t)row * D;
    f32x2 v = *(const f32x2*)(kr + lane * 2);
    float ss = v.x * v.x + v.y * v.y;
    #pragma unroll
    for (int o = 1; o < 64; o <<= 1) ss += __shfl_xor(ss, o);
    float inv = 1.0f / fmaxf(sqrtf(ss), 1e-12f);
    if (lane == 0) invk[row] = inv;
    u32 packed = (u32)f2bf(v.x * inv) | ((u32)f2bf(v.y * inv) << 16);
    *(u32*)(kn + (size_t)row * D + lane * 2) = packed;
}

// ---------------- kernel 2: MFMA sims + per-stream top-4 candidates ---------
// Block: 256 thr = 4 waves. Block handles 64 queries x one key partition.
// Wave w: 16 queries (qwb..qwb+15), iterates 64-key tiles.
// MFMA 16x16x32 bf16: A[i][k]: lane holds A[l&15][8*(l>>4)+j]; B[k][j]:
// B[8*(l>>4)+j][l&15]; D[i][j]: i=4*(l>>4)+r, j=l&15 (m89-verified).
__global__ __launch_bounds__(256) void k_select(
        const u16* __restrict__ kn, const float* __restrict__ q,
        u64* __restrict__ cand, int Q, int N, int P) {
    __shared__ __align__(16) char lds[64 * 256];  // 64 keys x 128 bf16, swizzled
    const int tid = threadIdx.x;
    const int wave = tid >> 6, lane = tid & 63;
    const int lrow = lane & 15, lhi = lane >> 4;
    const int nqb = Q >> 6;
    const int p  = blockIdx.x / nqb;
    const int qb = blockIdx.x % nqb;
    const int part = N / P;
    const int key0 = p * part;
    const int qwb = (qb << 6) + (wave << 4);

    // A fragments: raw q rows converted to bf16 on the fly (top-k is
    // invariant to the positive 1/|q| scale; applied exactly in k_final).
    s16x8 afr[4];
    {
        const float* qrow = q + (size_t)(qwb + lrow) * D + lhi * 8;
        #pragma unroll
        for (int s = 0; s < 4; ++s) {
            f32x4 a = *(const f32x4*)(qrow + s * 32);
            f32x4 b = *(const f32x4*)(qrow + s * 32 + 4);
            union { s16x8 v; u16 e[8]; } cv;
            cv.e[0]=f2bf(a.x); cv.e[1]=f2bf(a.y); cv.e[2]=f2bf(a.z); cv.e[3]=f2bf(a.w);
            cv.e[4]=f2bf(b.x); cv.e[5]=f2bf(b.y); cv.e[6]=f2bf(b.z); cv.e[7]=f2bf(b.w);
            afr[s] = cv.v;
        }
    }

    // per-lane top-4 (packed (ford(val)<<32)|key) for each of 4 owned queries
    u64 c0[4], c1[4], c2[4], c3[4];
    #pragma unroll
    for (int r = 0; r < 4; ++r) { c0[r]=0; c1[r]=0; c2[r]=0; c3[r]=0; }

    const int iters = part >> 6;
    const int srow = tid >> 2;            // staging: row 0..63
    const int sg0  = (tid & 3) << 2;      // granule col 0,4,8,12

    for (int kb = 0; kb < iters; ++kb) {
        const int keybase = key0 + (kb << 6);
        __syncthreads();
        {   // stage 64x256B, XOR-swizzle 16B granules within each row
            const u16* src = kn + (size_t)(keybase + srow) * D + sg0 * 8;
            #pragma unroll
            for (int i = 0; i < 4; ++i) {
                i32x4 v = *(const i32x4*)(src + i * 8);
                int sw = (sg0 + i) ^ (srow & 7);
                *(i32x4*)(lds + srow * 256 + (sw << 4)) = v;
            }
        }
        __syncthreads();
        #pragma unroll
        for (int kt = 0; kt < 4; ++kt) {
            const int rl = (kt << 4) + lrow;
            const char* rbase = lds + rl * 256;
            const int rx = rl & 7;
            f32x4 acc = {0.f, 0.f, 0.f, 0.f};
            #pragma unroll
            for (int s = 0; s < 4; ++s) {
                int g = (s << 2) + lhi;
                s16x8 bfr = *(const s16x8*)(rbase + ((g ^ rx) << 4));
                acc = __builtin_amdgcn_mfma_f32_16x16x32_bf16(afr[s], bfr, acc, 0, 0, 0);
            }
            const u32 key = (u32)(keybase + (kt << 4) + lrow);
            #pragma unroll
            for (int r = 0; r < 4; ++r) {
                u64 v = ((u64)ford(acc[r]) << 32) | key;
                if (v > c3[r]) {                 // rare -> cheap divergence
                    if (v > c1[r]) {
                        c3[r] = c2[r]; c2[r] = c1[r];
                        if (v > c0[r]) { c1[r] = c0[r]; c0[r] = v; } else c1[r] = v;
                    } else {
                        if (v > c2[r]) { c3[r] = c2[r]; c2[r] = v; } else c3[r] = v;
                    }
                }
            }
        }
    }
    #pragma unroll
    for (int r = 0; r < 4; ++r) {
        int qq = qwb + (lhi << 2) + r;
        u64* dst = cand + (((size_t)qq * P + p) << 6) + (lrow << 2);
        dst[0] = c0[r]; dst[1] = c1[r]; dst[2] = c2[r]; dst[3] = c3[r];
    }
}

// ---------------- kernel 3: merge -> top-16 -> exact refine -> output -------
template<int P>
__global__ __launch_bounds__(256) void k_final(
        const float* __restrict__ q, const float* __restrict__ keys,
        const float* __restrict__ vals, const float* __restrict__ invk,
        const u64* __restrict__ cand, float* __restrict__ pred,
        float* __restrict__ conf, int Q) {
    const int w = threadIdx.x >> 6;
    const int qq = blockIdx.x * 4 + w;
    const int lane = threadIdx.x & 63;
    __shared__ float qs[4][D];

    const float* qrow = q + (size_t)qq * D;
    f32x2 qv = *(const f32x2*)(qrow + lane * 2);
    qs[w][lane * 2] = qv.x; qs[w][lane * 2 + 1] = qv.y;
    float ss = qv.x * qv.x + qv.y * qv.y;
    #pragma unroll
    for (int o = 1; o < 64; o <<= 1) ss += __shfl_xor(ss, o);
    const float invq = 1.0f / fmaxf(sqrtf(ss), 1e-12f);
    __syncthreads();

    // load this query's P*64 candidates (P per lane)
    u64 a[P];
    const u64* cq = cand + (size_t)qq * (P * 64);
    #pragma unroll
    for (int k = 0; k < P; ++k) a[k] = cq[k * 64 + lane];

    // extract top-16 by bf16 sim; lane (l&15)==r remembers survivor r's key
    u32 mykey = 0;
    #pragma unroll
    for (int r = 0; r < 16; ++r) {
        u64 h = a[0];
        #pragma unroll
        for (int k = 1; k < P; ++k) h = a[k] > h ? a[k] : h;
        #pragma unroll
        for (int o = 1; o < 64; o <<= 1) {
            u64 t = __shfl_xor(h, o);
            h = t > h ? t : h;
        }
        if ((lane & 15) == r) mykey = (u32)h;
        #pragma unroll
        for (int k = 0; k < P; ++k) if (a[k] == h) a[k] = 0;   // pop (unique)
    }

    // exact fp32 sims for 16 survivors: 4 lanes per candidate (32 d each)
    const int ph = lane >> 4;
    const float* kr = keys + (size_t)mykey * D + ph * 32;
    const float* qsp = &qs[w][ph * 32];
    float dot = 0.f;
    #pragma unroll
    for (int j = 0; j < 32; j += 4) {
        f32x4 kv = *(const f32x4*)(kr + j);
        dot += kv.x * qsp[j] + kv.y * qsp[j + 1] + kv.z * qsp[j + 2] + kv.w * qsp[j + 3];
    }
    dot += __shfl_xor(dot, 16);
    dot += __shfl_xor(dot, 32);
    const float ex = dot * invk[mykey] * invq;
    // pack with ~key so ties prefer the smaller index (jax top_k order)
    u64 pk = ((u64)ford(ex) << 32) | (u32)(~mykey);

    float accA = 0.f, accB = 0.f, wsum = 0.f, vsum = 0.f, vmax = 0.f;
    #pragma unroll
    for (int r = 0; r < 8; ++r) {
        u64 h = pk;
        #pragma unroll
        for (int o = 1; o < 64; o <<= 1) {
            u64 t = __shfl_xor(h, o);
            h = t > h ? t : h;
        }
        const float v = ford_inv((u32)(h >> 32));
        const u32 idx = ~((u32)h);
        if (r == 0) vmax = v;
        const float wgt = expf(v - vmax);
        wsum += wgt; vsum += v;
        const float* vr = vals + (size_t)idx * D;
        accA += wgt * vr[lane];
        accB += wgt * vr[lane + 64];
        if (mykey == idx) pk = 0;   // pop winner (all 4 dup lanes)
    }
    const float inv_ws = 1.0f / wsum;
    pred[(size_t)qq * D + lane] = accA * inv_ws;
    pred[(size_t)qq * D + lane + 64] = accB * inv_ws;
    if (lane == 0) conf[qq] = fminf(fmaxf(vsum * 0.125f, 0.f), 1.f);
}

// ---------------------------------------------------------------------------
extern "C" void kernel_launch(void* const* d_in, const int* in_sizes, int n_in,
                              void* d_out, int out_size, void* d_ws, size_t ws_size,
                              hipStream_t stream) {
    const float* q    = (const float*)d_in[0];
    const float* keys = (const float*)d_in[1];
    const float* vals = (const float*)d_in[2];
    const int Q = in_sizes[0] / D;
    const int N = in_sizes[1] / D;

    char* ws = (char*)d_ws;
    const size_t knB = (size_t)N * D * 2;
    const size_t ivB = (size_t)N * 4;
    u16*   kn   = (u16*)ws;
    float* invk = (float*)(ws + knB);
    u64*   cand = (u64*)(ws + knB + ivB);

    int P = 16;  // partitions; shrink if ws is tight (occupancy drops, stays correct)
    while (P > 1 && knB + ivB + ((size_t)Q * P * 64 * 8) > ws_size) P >>= 1;

    float* pred = (float*)d_out;
    float* conf = pred + (size_t)Q * D;

    k_norm_keys<<<(N + 3) / 4, 256, 0, stream>>>(keys, kn, invk, N);
    k_select<<<(Q / 64) * P, 256, 0, stream>>>(kn, q, cand, Q, N, P);
    switch (P) {
        case 16: k_final<16><<<Q / 4, 256, 0, stream>>>(q, keys, vals, invk, cand, pred, conf, Q); break;
        case 8:  k_final<8> <<<Q / 4, 256, 0, stream>>>(q, keys, vals, invk, cand, pred, conf, Q); break;
        case 4:  k_final<4> <<<Q / 4, 256, 0, stream>>>(q, keys, vals, invk, cand, pred, conf, Q); break;
        case 2:  k_final<2> <<<Q / 4, 256, 0, stream>>>(q, keys, vals, invk, cand, pred, conf, Q); break;
        default: k_final<1> <<<Q / 4, 256, 0, stream>>>(q, keys, vals, invk, cand, pred, conf, Q); break;
    }
}

// Round 2
// 241.433 us; speedup vs baseline: 1.7382x; 1.7382x over previous
//
#include <hip/hip_runtime.h>
#include <stdint.h>

// Two-pass select-by-threshold pipeline:
//   k_norm_keys : exact fp32 normalize keys -> bf16 kn + invk; zero cnt
//   k_pass1     : bf16 MFMA sims; per-stream (q, j, kt, p) running MAX only
//                 (1 v_max per pair, branchless, no index tracking)
//   k_thresh    : per query, T = 8th-largest of 1024 stream maxima - margin.
//                 T <= v8 guaranteed (8 largest stream-maxima are 8 distinct
//                 keys' sims), so count(sim>=T) >= 8; count <= ~16 w.h.p.
//   k_pass2     : recompute identical sims; append keys with sim >= T via
//                 rare atomicAdd (approx 10 appends/query of 65536 keys)
//   k_final     : exact fp32 re-dot of <=32 candidates -> top-8, softmax,
//                 gather vals, conf  (selection invariant to q scale; exact
//                 1/|q|,1/|k| applied here)
// ws: [kn: N*256B][invk: N*4][smax: Q*1024*4][thr: Q*4][cnt: Q*4][cbuf: Q*32*4]

typedef unsigned int u32;
typedef unsigned long long u64;
typedef unsigned short u16;
typedef __attribute__((ext_vector_type(4))) float f32x4;
typedef __attribute__((ext_vector_type(2))) float f32x2;
typedef __attribute__((ext_vector_type(4))) int i32x4;
typedef __attribute__((ext_vector_type(8))) short s16x8;  // 8 bf16 in 4 VGPRs

#define D 128
#define PPART 16     // key partitions
#define CMAX 32      // candidate buffer per query
#define MARGIN 0.05f // bf16-rounding safety margin on threshold

__device__ __forceinline__ u16 f2bf(float f) {           // RNE float->bf16
    u32 b = __float_as_uint(f);
    b += 0x7FFFu + ((b >> 16) & 1u);
    return (u16)(b >> 16);
}
__device__ __forceinline__ u32 ford(float f) {            // order-preserving f32->u32
    u32 b = __float_as_uint(f);
    return (b & 0x80000000u) ? ~b : (b | 0x80000000u);
}
__device__ __forceinline__ float ford_inv(u32 ob) {
    u32 b = (ob & 0x80000000u) ? (ob ^ 0x80000000u) : ~ob;
    return __uint_as_float(b);
}

// ---------------- kernel 1: normalize keys -> bf16, invk; zero cnt ----------
__global__ __launch_bounds__(256) void k_norm_keys(
        const float* __restrict__ keys, u16* __restrict__ kn,
        float* __restrict__ invk, u32* __restrict__ cnt, int N, int Q) {
    int row = blockIdx.x * 4 + (threadIdx.x >> 6);
    int lane = threadIdx.x & 63;
    if (row >= N) return;
    if (row < Q && lane == 0) cnt[row] = 0u;
    const float* kr = keys + (size_t)row * D;
    f32x2 v = *(const f32x2*)(kr + lane * 2);
    float ss = v.x * v.x + v.y * v.y;
    #pragma unroll
    for (int o = 1; o < 64; o <<= 1) ss += __shfl_xor(ss, o);
    float inv = 1.0f / fmaxf(sqrtf(ss), 1e-12f);
    if (lane == 0) invk[row] = inv;
    u32 packed = (u32)f2bf(v.x * inv) | ((u32)f2bf(v.y * inv) << 16);
    *(u32*)(kn + (size_t)row * D + lane * 2) = packed;
}

// Shared staging + fragment helpers --------------------------------------
// LDS tile: 64 key-rows x 256 B, 16B granules XOR-swizzled: slot(row, col)
// holds global granule col, stored at col^(row&15)  (bijective; read lanes
// lrow=0..15 hit 16 distinct granule columns -> conflict-free b128 reads).

__device__ __forceinline__ void load_afr(const float* q, int qrow_base,
                                         int lrow, int lhi, s16x8 afr[4]) {
    const float* qrow = q + (size_t)(qrow_base + lrow) * D + lhi * 8;
    #pragma unroll
    for (int s = 0; s < 4; ++s) {
        f32x4 a = *(const f32x4*)(qrow + s * 32);
        f32x4 b = *(const f32x4*)(qrow + s * 32 + 4);
        union { s16x8 v; u16 e[8]; } cv;
        cv.e[0]=f2bf(a.x); cv.e[1]=f2bf(a.y); cv.e[2]=f2bf(a.z); cv.e[3]=f2bf(a.w);
        cv.e[4]=f2bf(b.x); cv.e[5]=f2bf(b.y); cv.e[6]=f2bf(b.z); cv.e[7]=f2bf(b.w);
        afr[s] = cv.v;
    }
}

// ---------------- kernel 2: pass 1 — per-stream max ------------------------
__global__ __launch_bounds__(256) void k_pass1(
        const u16* __restrict__ kn, const float* __restrict__ q,
        float* __restrict__ smax, int Q, int N) {
    __shared__ __align__(16) char lds[64 * 256];
    const int tid = threadIdx.x;
    const int wave = tid >> 6, lane = tid & 63;
    const int lrow = lane & 15, lhi = lane >> 4;
    const int nqb = Q >> 6;
    const int p  = blockIdx.x / nqb;
    const int qb = blockIdx.x % nqb;
    const int part = N / PPART;
    const int key0 = p * part;
    const int qwb = (qb << 6) + (wave << 4);

    s16x8 afr[4];
    load_afr(q, qwb, lrow, lhi, afr);

    float m[4][4];
    #pragma unroll
    for (int kt = 0; kt < 4; ++kt)
        #pragma unroll
        for (int r = 0; r < 4; ++r) m[kt][r] = -3.0e38f;

    // lane-constant LDS read bases (kt handled by offset immediate)
    const char* rb[4];
    #pragma unroll
    for (int s = 0; s < 4; ++s)
        rb[s] = lds + lrow * 256 + ((((s << 2) + lhi) ^ lrow) << 4);

    const int iters = part >> 6;
    const int srow = tid >> 2;
    const int sg0  = (tid & 3) << 2;
    const u16* src = kn + (size_t)(key0 + srow) * D + sg0 * 8;
    char* wdst[4];
    #pragma unroll
    for (int i = 0; i < 4; ++i)
        wdst[i] = lds + srow * 256 + (((sg0 + i) ^ (srow & 15)) << 4);

    for (int kb = 0; kb < iters; ++kb) {
        __syncthreads();
        #pragma unroll
        for (int i = 0; i < 4; ++i)
            *(i32x4*)wdst[i] = *(const i32x4*)(src + i * 8);
        src += 64 * D;
        __syncthreads();
        #pragma unroll
        for (int kt = 0; kt < 4; ++kt) {
            f32x4 acc = {0.f, 0.f, 0.f, 0.f};
            #pragma unroll
            for (int s = 0; s < 4; ++s) {
                s16x8 bfr = *(const s16x8*)(rb[s] + kt * 4096);
                acc = __builtin_amdgcn_mfma_f32_16x16x32_bf16(afr[s], bfr, acc, 0, 0, 0);
            }
            #pragma unroll
            for (int r = 0; r < 4; ++r) m[kt][r] = fmaxf(m[kt][r], acc[r]);
        }
    }
    #pragma unroll
    for (int kt = 0; kt < 4; ++kt)
        #pragma unroll
        for (int r = 0; r < 4; ++r) {
            int qq = qwb + (lhi << 2) + r;
            smax[(size_t)qq * 1024 + p * 64 + kt * 16 + lrow] = m[kt][r];
        }
}

// ---------------- kernel 3: per-query threshold -----------------------------
__global__ __launch_bounds__(256) void k_thresh(
        const float* __restrict__ smax, float* __restrict__ thr, int Q) {
    const int wave = threadIdx.x >> 6, lane = threadIdx.x & 63;
    const int qq = blockIdx.x * 4 + wave;
    const float* sq = smax + (size_t)qq * 1024;
    float v[16];
    #pragma unroll
    for (int i = 0; i < 16; ++i) v[i] = sq[i * 64 + lane];
    float h = -3.0e38f;
    #pragma unroll
    for (int round = 0; round < 8; ++round) {
        h = v[0];
        #pragma unroll
        for (int i = 1; i < 16; ++i) h = fmaxf(h, v[i]);
        #pragma unroll
        for (int o = 1; o < 64; o <<= 1) h = fmaxf(h, __shfl_xor(h, o));
        #pragma unroll
        for (int i = 0; i < 16; ++i) if (v[i] == h) v[i] = -3.0e38f;  // knockout (dups collapse -> T smaller = safe)
    }
    if (lane == 0) thr[qq] = h - MARGIN;
}

// ---------------- kernel 4: pass 2 — threshold collect ----------------------
__global__ __launch_bounds__(256) void k_pass2(
        const u16* __restrict__ kn, const float* __restrict__ q,
        const float* __restrict__ thr, u32* __restrict__ cnt,
        u32* __restrict__ cbuf, int Q, int N) {
    __shared__ __align__(16) char lds[64 * 256];
    const int tid = threadIdx.x;
    const int wave = tid >> 6, lane = tid & 63;
    const int lrow = lane & 15, lhi = lane >> 4;
    const int nqb = Q >> 6;
    const int p  = blockIdx.x / nqb;
    const int qb = blockIdx.x % nqb;
    const int part = N / PPART;
    const int key0 = p * part;
    const int qwb = (qb << 6) + (wave << 4);

    s16x8 afr[4];
    load_afr(q, qwb, lrow, lhi, afr);

    float t[4];
    #pragma unroll
    for (int r = 0; r < 4; ++r) t[r] = thr[qwb + (lhi << 2) + r];

    const char* rb[4];
    #pragma unroll
    for (int s = 0; s < 4; ++s)
        rb[s] = lds + lrow * 256 + ((((s << 2) + lhi) ^ lrow) << 4);

    const int iters = part >> 6;
    const int srow = tid >> 2;
    const int sg0  = (tid & 3) << 2;
    const u16* src = kn + (size_t)(key0 + srow) * D + sg0 * 8;
    char* wdst[4];
    #pragma unroll
    for (int i = 0; i < 4; ++i)
        wdst[i] = lds + srow * 256 + (((sg0 + i) ^ (srow & 15)) << 4);

    for (int kb = 0; kb < iters; ++kb) {
        __syncthreads();
        #pragma unroll
        for (int i = 0; i < 4; ++i)
            *(i32x4*)wdst[i] = *(const i32x4*)(src + i * 8);
        src += 64 * D;
        __syncthreads();
        const int keybase = key0 + (kb << 6);
        #pragma unroll
        for (int kt = 0; kt < 4; ++kt) {
            f32x4 acc = {0.f, 0.f, 0.f, 0.f};
            #pragma unroll
            for (int s = 0; s < 4; ++s) {
                s16x8 bfr = *(const s16x8*)(rb[s] + kt * 4096);
                acc = __builtin_amdgcn_mfma_f32_16x16x32_bf16(afr[s], bfr, acc, 0, 0, 0);
            }
            // rare: ~4% of kt-checks have any passing lane
            if ((acc[0] >= t[0]) | (acc[1] >= t[1]) | (acc[2] >= t[2]) | (acc[3] >= t[3])) {
                const u32 key = (u32)(keybase + (kt << 4) + lrow);
                #pragma unroll
                for (int r = 0; r < 4; ++r) {
                    if (acc[r] >= t[r]) {
                        int qq = qwb + (lhi << 2) + r;
                        u32 pos = atomicAdd(&cnt[qq], 1u);
                        if (pos < CMAX) cbuf[(size_t)qq * CMAX + pos] = key;
                    }
                }
            }
        }
    }
}

// ---------------- kernel 5: exact refine -> top-8 -> output -----------------
__global__ __launch_bounds__(256) void k_final(
        const float* __restrict__ q, const float* __restrict__ keys,
        const float* __restrict__ vals, const float* __restrict__ invk,
        const u32* __restrict__ cnt, const u32* __restrict__ cbuf,
        float* __restrict__ pred, float* __restrict__ conf, int Q) {
    const int w = threadIdx.x >> 6;
    const int qq = blockIdx.x * 4 + w;
    const int lane = threadIdx.x & 63;
    __shared__ float qs[4][D];

    const float* qrow = q + (size_t)qq * D;
    f32x2 qv = *(const f32x2*)(qrow + lane * 2);
    qs[w][lane * 2] = qv.x; qs[w][lane * 2 + 1] = qv.y;
    float ss = qv.x * qv.x + qv.y * qv.y;
    #pragma unroll
    for (int o = 1; o < 64; o <<= 1) ss += __shfl_xor(ss, o);
    const float invq = 1.0f / fmaxf(sqrtf(ss), 1e-12f);
    __syncthreads();

    const u32 n = min(cnt[qq], (u32)CMAX);   // guaranteed >= 8 by construction
    const int c = lane >> 1;                 // candidate id (2 lanes each)
    const int half = lane & 1;
    const bool valid = (u32)c < n;
    const u32 key = valid ? cbuf[(size_t)qq * CMAX + c] : 0u;

    // exact fp32 dot: 2 lanes x 64 dims
    const float* kr = keys + (size_t)key * D + half * 64;
    const float* qsp = &qs[w][half * 64];
    float dot = 0.f;
    #pragma unroll
    for (int j = 0; j < 64; j += 4) {
        f32x4 kv = *(const f32x4*)(kr + j);
        dot += kv.x * qsp[j] + kv.y * qsp[j + 1] + kv.z * qsp[j + 2] + kv.w * qsp[j + 3];
    }
    dot += __shfl_xor(dot, 1);
    const float ex = dot * invk[key] * invq;
    // pack with ~key so ties prefer the smaller index (jax top_k order)
    u64 pk = valid ? (((u64)ford(ex) << 32) | (u32)(~key)) : 0ull;

    float accA = 0.f, accB = 0.f, wsum = 0.f, vsum = 0.f, vmax = 0.f;
    #pragma unroll
    for (int r = 0; r < 8; ++r) {
        u64 h = pk;
        #pragma unroll
        for (int o = 1; o < 64; o <<= 1) {
            u64 tt = __shfl_xor(h, o);
            h = tt > h ? tt : h;
        }
        const bool ok = (h != 0ull);
        const float v = ford_inv((u32)(h >> 32));
        const u32 idx = ok ? ~((u32)h) : 0u;
        if (r == 0) vmax = v;
        const float wgt = ok ? expf(v - vmax) : 0.f;
        wsum += wgt; vsum += ok ? v : 0.f;
        const float* vr = vals + (size_t)idx * D;
        accA += wgt * vr[lane];
        accB += wgt * vr[lane + 64];
        if (pk == h) pk = 0ull;   // pop winner (both dup lanes)
    }
    const float inv_ws = 1.0f / wsum;
    pred[(size_t)qq * D + lane] = accA * inv_ws;
    pred[(size_t)qq * D + lane + 64] = accB * inv_ws;
    if (lane == 0) conf[qq] = fminf(fmaxf(vsum * 0.125f, 0.f), 1.f);
}

// ---------------------------------------------------------------------------
extern "C" void kernel_launch(void* const* d_in, const int* in_sizes, int n_in,
                              void* d_out, int out_size, void* d_ws, size_t ws_size,
                              hipStream_t stream) {
    const float* q    = (const float*)d_in[0];
    const float* keys = (const float*)d_in[1];
    const float* vals = (const float*)d_in[2];
    const int Q = in_sizes[0] / D;
    const int N = in_sizes[1] / D;

    char* ws = (char*)d_ws;
    size_t off = 0;
    u16*   kn   = (u16*)(ws + off);  off += (size_t)N * D * 2;
    float* invk = (float*)(ws + off); off += (size_t)N * 4;
    float* smax = (float*)(ws + off); off += (size_t)Q * 1024 * 4;
    float* thr  = (float*)(ws + off); off += (size_t)Q * 4;
    u32*   cnt  = (u32*)(ws + off);   off += (size_t)Q * 4;
    u32*   cbuf = (u32*)(ws + off);   off += (size_t)Q * CMAX * 4;

    float* pred = (float*)d_out;
    float* conf = pred + (size_t)Q * D;

    k_norm_keys<<<(N + 3) / 4, 256, 0, stream>>>(keys, kn, invk, cnt, N, Q);
    k_pass1<<<(Q / 64) * PPART, 256, 0, stream>>>(kn, q, smax, Q, N);
    k_thresh<<<Q / 4, 256, 0, stream>>>(smax, thr, Q);
    k_pass2<<<(Q / 64) * PPART, 256, 0, stream>>>(kn, q, thr, cnt, cbuf, Q, N);
    k_final<<<Q / 4, 256, 0, stream>>>(q, keys, vals, invk, cnt, cbuf, pred, conf, Q);
}

// Round 4
// 201.293 us; speedup vs baseline: 2.0848x; 1.1994x over previous
//
#include <hip/hip_runtime.h>
#include <stdint.h>

// Two-pass select-by-threshold pipeline (R4: R3 structure, R2-proven register
// staging — ds_write_b128 swizzled writes instead of global_load_lds):
//   k_norm_keys : exact fp32 normalize keys -> bf16 kn + invk; zero cnt
//   k_pass1     : bf16 MFMA sims; per-stream running MAX (1 v_max per result)
//   k_thresh    : T = 8th-largest of PPART*64 stream maxima - margin
//   k_pass2     : recompute bit-identical sims; collect keys >= T (rare atomics)
//   k_final     : exact fp32 re-dot of <=32 candidates -> top-8, softmax, gather
// ws: [kn N*256B][invk N*4][smax Q*PPART*64*4][thr Q*4][cnt Q*4][cbuf Q*32*4]

typedef unsigned int u32;
typedef unsigned long long u64;
typedef unsigned short u16;
typedef __attribute__((ext_vector_type(4))) float f32x4;
typedef __attribute__((ext_vector_type(2))) float f32x2;
typedef __attribute__((ext_vector_type(4))) int i32x4;
typedef __attribute__((ext_vector_type(8))) short s16x8;  // 8 bf16 in 4 VGPRs

#define D 128
#define KTILE 128    // keys per LDS tile (32 KB)
#define QW 64        // queries per wave
#define QB 256       // queries per block (4 waves)
#define CMAX 32      // candidate buffer per query
#define MARGIN 0.05f // threshold safety margin (cheap: a few extra candidates)

__device__ __forceinline__ u16 f2bf(float f) {           // RNE float->bf16
    u32 b = __float_as_uint(f);
    b += 0x7FFFu + ((b >> 16) & 1u);
    return (u16)(b >> 16);
}
__device__ __forceinline__ u32 ford(float f) {            // order-preserving f32->u32
    u32 b = __float_as_uint(f);
    return (b & 0x80000000u) ? ~b : (b | 0x80000000u);
}
__device__ __forceinline__ float ford_inv(u32 ob) {
    u32 b = (ob & 0x80000000u) ? (ob ^ 0x80000000u) : ~ob;
    return __uint_as_float(b);
}

// ---------------- kernel 1: normalize keys -> bf16, invk; zero cnt ----------
__global__ __launch_bounds__(256) void k_norm_keys(
        const float* __restrict__ keys, u16* __restrict__ kn,
        float* __restrict__ invk, u32* __restrict__ cnt, int N, int Q) {
    int row = blockIdx.x * 4 + (threadIdx.x >> 6);
    int lane = threadIdx.x & 63;
    if (row >= N) return;
    if (row < Q && lane == 0) cnt[row] = 0u;
    const float* kr = keys + (size_t)row * D;
    f32x2 v = *(const f32x2*)(kr + lane * 2);
    float ss = v.x * v.x + v.y * v.y;
    #pragma unroll
    for (int o = 1; o < 64; o <<= 1) ss += __shfl_xor(ss, o);
    float inv = 1.0f / fmaxf(sqrtf(ss), 1e-12f);
    if (lane == 0) invk[row] = inv;
    u32 packed = (u32)f2bf(v.x * inv) | ((u32)f2bf(v.y * inv) << 16);
    *(u32*)(kn + (size_t)row * D + lane * 2) = packed;
}

// A fragments: raw q rows -> bf16 (selection is invariant to the positive
// 1/|q| scale; exact scale applied in k_final).
__device__ __forceinline__ void load_afr(const float* q, int qrow_base,
                                         int lrow, int lhi, s16x8 afr[4]) {
    const float* qrow = q + (size_t)(qrow_base + lrow) * D + lhi * 8;
    #pragma unroll
    for (int s = 0; s < 4; ++s) {
        f32x4 a = *(const f32x4*)(qrow + s * 32);
        f32x4 b = *(const f32x4*)(qrow + s * 32 + 4);
        union { s16x8 v; u16 e[8]; } cv;
        cv.e[0]=f2bf(a.x); cv.e[1]=f2bf(a.y); cv.e[2]=f2bf(a.z); cv.e[3]=f2bf(a.w);
        cv.e[4]=f2bf(b.x); cv.e[5]=f2bf(b.y); cv.e[6]=f2bf(b.z); cv.e[7]=f2bf(b.w);
        afr[s] = cv.v;
    }
}

// LDS swizzle contract: slot (row r, 16B-granule g) holds global granule
// g ^ (r&15).  Writes: register-staged ds_write_b128 at granule (g^(r&15)).
// Reads: slot granule (4s+lhi)^lrow at row kt*16+lrow -> global chunk 4s+lhi
// (conflict-free b128 both sides; write rows spread banks via (row&7)).

// ---------------- kernel 2: pass 1 — per-stream max ------------------------
__global__ __launch_bounds__(256, 2) void k_pass1(
        const u16* __restrict__ kn, const float* __restrict__ q,
        float* __restrict__ smax, int Q, int N, int PPART) {
    __shared__ __align__(16) char lds[KTILE * 256];
    const int tid = threadIdx.x;
    const int wave = tid >> 6, lane = tid & 63;
    const int lrow = lane & 15, lhi = lane >> 4;
    const int nqb = Q / QB;
    const int p  = blockIdx.x / nqb;
    const int qb = blockIdx.x % nqb;
    const int part = N / PPART;
    const int key0 = p * part;
    const int qbase = qb * QB + wave * QW;

    s16x8 afr[4][4];
    #pragma unroll
    for (int qs = 0; qs < 4; ++qs) load_afr(q, qbase + qs * 16, lrow, lhi, afr[qs]);

    float m[4][4][4];
    #pragma unroll
    for (int qs = 0; qs < 4; ++qs)
        #pragma unroll
        for (int k2 = 0; k2 < 4; ++k2)
            #pragma unroll
            for (int r = 0; r < 4; ++r) m[qs][k2][r] = -3.0e38f;

    const char* rb[4];
    #pragma unroll
    for (int s = 0; s < 4; ++s)
        rb[s] = lds + lrow * 256 + ((((s << 2) + lhi) ^ lrow) << 4);

    // staging: thread t -> row t>>1, granules (t&1)*8 + 0..7 (128B contiguous)
    const int srow = tid >> 1;
    const int sgb  = (tid & 1) << 3;
    const int sx   = srow & 15;
    char* wbase = lds + srow * 256;
    const char* gsrc = (const char*)kn + ((size_t)(key0 + srow)) * 256 + sgb * 16;

    const int iters = part / KTILE;
    i32x4 v[8];
    #pragma unroll
    for (int i = 0; i < 8; ++i) v[i] = *(const i32x4*)(gsrc + i * 16);

    for (int kb = 0; kb < iters; ++kb) {
        __syncthreads();   // all waves done reading previous tile
        #pragma unroll
        for (int i = 0; i < 8; ++i)
            *(i32x4*)(wbase + (((sgb + i) ^ sx) << 4)) = v[i];
        __syncthreads();   // writes drained
        // prefetch next tile into regs: in flight across the MFMA phase
        const char* gn = gsrc + (size_t)((kb + 1 < iters) ? kb + 1 : kb) * (KTILE * 256);
        #pragma unroll
        for (int i = 0; i < 8; ++i) v[i] = *(const i32x4*)(gn + i * 16);
        #pragma unroll
        for (int kt = 0; kt < 8; ++kt) {
            s16x8 bfr[4];
            #pragma unroll
            for (int s = 0; s < 4; ++s) bfr[s] = *(const s16x8*)(rb[s] + kt * 4096);
            #pragma unroll
            for (int qs = 0; qs < 4; ++qs) {
                f32x4 acc = {0.f, 0.f, 0.f, 0.f};
                #pragma unroll
                for (int s = 0; s < 4; ++s)
                    acc = __builtin_amdgcn_mfma_f32_16x16x32_bf16(afr[qs][s], bfr[s], acc, 0, 0, 0);
                #pragma unroll
                for (int r = 0; r < 4; ++r)
                    m[qs][kt & 3][r] = fmaxf(m[qs][kt & 3][r], acc[r]);
            }
        }
    }
    const int stride = PPART * 64;
    #pragma unroll
    for (int qs = 0; qs < 4; ++qs)
        #pragma unroll
        for (int k2 = 0; k2 < 4; ++k2)
            #pragma unroll
            for (int r = 0; r < 4; ++r) {
                int qq = qbase + qs * 16 + (lhi << 2) + r;
                smax[(size_t)qq * stride + p * 64 + k2 * 16 + lrow] = m[qs][k2][r];
            }
}

// ---------------- kernel 3: per-query threshold -----------------------------
__global__ __launch_bounds__(256) void k_thresh(
        const float* __restrict__ smax, float* __restrict__ thr, int PP) {
    const int wave = threadIdx.x >> 6, lane = threadIdx.x & 63;
    const int qq = blockIdx.x * 4 + wave;
    const float* sq = smax + (size_t)qq * (PP * 64);
    float v[32];
    #pragma unroll
    for (int i = 0; i < 32; ++i) v[i] = (i < PP) ? sq[i * 64 + lane] : -3.0e38f;
    float h = -3.0e38f;
    #pragma unroll
    for (int round = 0; round < 8; ++round) {
        h = v[0];
        #pragma unroll
        for (int i = 1; i < 32; ++i) h = fmaxf(h, v[i]);
        #pragma unroll
        for (int o = 1; o < 64; o <<= 1) h = fmaxf(h, __shfl_xor(h, o));
        #pragma unroll
        for (int i = 0; i < 32; ++i) if (v[i] == h) v[i] = -3.0e38f;  // knockout
    }
    if (lane == 0) thr[qq] = h - MARGIN;
}

// ---------------- kernel 4: pass 2 — threshold collect ----------------------
__global__ __launch_bounds__(256, 2) void k_pass2(
        const u16* __restrict__ kn, const float* __restrict__ q,
        const float* __restrict__ thr, u32* __restrict__ cnt,
        u32* __restrict__ cbuf, int Q, int N, int PPART) {
    __shared__ __align__(16) char lds[KTILE * 256];
    const int tid = threadIdx.x;
    const int wave = tid >> 6, lane = tid & 63;
    const int lrow = lane & 15, lhi = lane >> 4;
    const int nqb = Q / QB;
    const int p  = blockIdx.x / nqb;
    const int qb = blockIdx.x % nqb;
    const int part = N / PPART;
    const int key0 = p * part;
    const int qbase = qb * QB + wave * QW;

    s16x8 afr[4][4];
    #pragma unroll
    for (int qs = 0; qs < 4; ++qs) load_afr(q, qbase + qs * 16, lrow, lhi, afr[qs]);

    f32x4 t[4];
    #pragma unroll
    for (int qs = 0; qs < 4; ++qs)
        t[qs] = *(const f32x4*)(thr + qbase + qs * 16 + (lhi << 2));

    const char* rb[4];
    #pragma unroll
    for (int s = 0; s < 4; ++s)
        rb[s] = lds + lrow * 256 + ((((s << 2) + lhi) ^ lrow) << 4);

    const int srow = tid >> 1;
    const int sgb  = (tid & 1) << 3;
    const int sx   = srow & 15;
    char* wbase = lds + srow * 256;
    const char* gsrc = (const char*)kn + ((size_t)(key0 + srow)) * 256 + sgb * 16;

    const int iters = part / KTILE;
    i32x4 v[8];
    #pragma unroll
    for (int i = 0; i < 8; ++i) v[i] = *(const i32x4*)(gsrc + i * 16);

    for (int kb = 0; kb < iters; ++kb) {
        __syncthreads();
        #pragma unroll
        for (int i = 0; i < 8; ++i)
            *(i32x4*)(wbase + (((sgb + i) ^ sx) << 4)) = v[i];
        __syncthreads();
        const char* gn = gsrc + (size_t)((kb + 1 < iters) ? kb + 1 : kb) * (KTILE * 256);
        #pragma unroll
        for (int i = 0; i < 8; ++i) v[i] = *(const i32x4*)(gn + i * 16);
        const int keybase = key0 + kb * KTILE;
        #pragma unroll
        for (int kt = 0; kt < 8; ++kt) {
            s16x8 bfr[4];
            #pragma unroll
            for (int s = 0; s < 4; ++s) bfr[s] = *(const s16x8*)(rb[s] + kt * 4096);
            #pragma unroll
            for (int qs = 0; qs < 4; ++qs) {
                f32x4 acc = {0.f, 0.f, 0.f, 0.f};
                #pragma unroll
                for (int s = 0; s < 4; ++s)
                    acc = __builtin_amdgcn_mfma_f32_16x16x32_bf16(afr[qs][s], bfr[s], acc, 0, 0, 0);
                if ((acc[0] >= t[qs][0]) | (acc[1] >= t[qs][1]) |
                    (acc[2] >= t[qs][2]) | (acc[3] >= t[qs][3])) {  // rare
                    const u32 key = (u32)(keybase + (kt << 4) + lrow);
                    #pragma unroll
                    for (int r = 0; r < 4; ++r) {
                        if (acc[r] >= t[qs][r]) {
                            int qq = qbase + qs * 16 + (lhi << 2) + r;
                            u32 pos = atomicAdd(&cnt[qq], 1u);
                            if (pos < CMAX) cbuf[(size_t)qq * CMAX + pos] = key;
                        }
                    }
                }
            }
        }
    }
}

// ---------------- kernel 5: exact refine -> top-8 -> output -----------------
__global__ __launch_bounds__(256) void k_final(
        const float* __restrict__ q, const float* __restrict__ keys,
        const float* __restrict__ vals, const float* __restrict__ invk,
        const u32* __restrict__ cnt, const u32* __restrict__ cbuf,
        float* __restrict__ pred, float* __restrict__ conf, int Q) {
    const int w = threadIdx.x >> 6;
    const int qq = blockIdx.x * 4 + w;
    const int lane = threadIdx.x & 63;
    __shared__ float qs[4][D];

    const float* qrow = q + (size_t)qq * D;
    f32x2 qv = *(const f32x2*)(qrow + lane * 2);
    qs[w][lane * 2] = qv.x; qs[w][lane * 2 + 1] = qv.y;
    float ss = qv.x * qv.x + qv.y * qv.y;
    #pragma unroll
    for (int o = 1; o < 64; o <<= 1) ss += __shfl_xor(ss, o);
    const float invq = 1.0f / fmaxf(sqrtf(ss), 1e-12f);
    __syncthreads();

    const u32 n = min(cnt[qq], (u32)CMAX);   // >= 8 by construction
    const int c = lane >> 1;                 // candidate id (2 lanes each)
    const int half = lane & 1;
    const bool valid = (u32)c < n;
    const u32 key = valid ? cbuf[(size_t)qq * CMAX + c] : 0u;

    const float* kr = keys + (size_t)key * D + half * 64;
    const float* qsp = &qs[w][half * 64];
    float dot = 0.f;
    #pragma unroll
    for (int j = 0; j < 64; j += 4) {
        f32x4 kv = *(const f32x4*)(kr + j);
        dot += kv.x * qsp[j] + kv.y * qsp[j + 1] + kv.z * qsp[j + 2] + kv.w * qsp[j + 3];
    }
    dot += __shfl_xor(dot, 1);
    const float ex = dot * invk[key] * invq;
    u64 pk = valid ? (((u64)ford(ex) << 32) | (u32)(~key)) : 0ull;

    float accA = 0.f, accB = 0.f, wsum = 0.f, vsum = 0.f, vmax = 0.f;
    #pragma unroll
    for (int r = 0; r < 8; ++r) {
        u64 h = pk;
        #pragma unroll
        for (int o = 1; o < 64; o <<= 1) {
            u64 tt = __shfl_xor(h, o);
            h = tt > h ? tt : h;
        }
        const bool ok = (h != 0ull);
        const float v = ford_inv((u32)(h >> 32));
        const u32 idx = ok ? ~((u32)h) : 0u;
        if (r == 0) vmax = v;
        const float wgt = ok ? expf(v - vmax) : 0.f;
        wsum += wgt; vsum += ok ? v : 0.f;
        const float* vr = vals + (size_t)idx * D;
        accA += wgt * vr[lane];
        accB += wgt * vr[lane + 64];
        if (pk == h) pk = 0ull;   // pop winner
    }
    const float inv_ws = 1.0f / wsum;
    pred[(size_t)qq * D + lane] = accA * inv_ws;
    pred[(size_t)qq * D + lane + 64] = accB * inv_ws;
    if (lane == 0) conf[qq] = fminf(fmaxf(vsum * 0.125f, 0.f), 1.f);
}

// ---------------------------------------------------------------------------
extern "C" void kernel_launch(void* const* d_in, const int* in_sizes, int n_in,
                              void* d_out, int out_size, void* d_ws, size_t ws_size,
                              hipStream_t stream) {
    const float* q    = (const float*)d_in[0];
    const float* keys = (const float*)d_in[1];
    const float* vals = (const float*)d_in[2];
    const int Q = in_sizes[0] / D;
    const int N = in_sizes[1] / D;

    int PPART = 32;  // 512 blocks = 2 blocks/CU; shrink if ws is tight
    auto need = [&](int P) {
        return (size_t)N * D * 2 + (size_t)N * 4 + (size_t)Q * P * 64 * 4 +
               (size_t)Q * 4 * 2 + (size_t)Q * CMAX * 4;
    };
    while (PPART > 2 && need(PPART) > ws_size) PPART >>= 1;

    char* ws = (char*)d_ws;
    size_t off = 0;
    u16*   kn   = (u16*)(ws + off);   off += (size_t)N * D * 2;
    float* invk = (float*)(ws + off); off += (size_t)N * 4;
    float* smax = (float*)(ws + off); off += (size_t)Q * PPART * 64 * 4;
    float* thr  = (float*)(ws + off); off += (size_t)Q * 4;
    u32*   cnt  = (u32*)(ws + off);   off += (size_t)Q * 4;
    u32*   cbuf = (u32*)(ws + off);   off += (size_t)Q * CMAX * 4;

    float* pred = (float*)d_out;
    float* conf = pred + (size_t)Q * D;

    k_norm_keys<<<(N + 3) / 4, 256, 0, stream>>>(keys, kn, invk, cnt, N, Q);
    k_pass1<<<(Q / QB) * PPART, 256, 0, stream>>>(kn, q, smax, Q, N, PPART);
    k_thresh<<<Q / 4, 256, 0, stream>>>(smax, thr, PPART);
    k_pass2<<<(Q / QB) * PPART, 256, 0, stream>>>(kn, q, thr, cnt, cbuf, Q, N, PPART);
    k_final<<<Q / 4, 256, 0, stream>>>(q, keys, vals, invk, cnt, cbuf, pred, conf, Q);
}